// Round 2
// baseline (19970.354 us; speedup 1.0000x reference)
//
#include <hip/hip_runtime.h>
#include <hip/hip_bf16.h>
#include <cstddef>

// ---------------- problem constants ----------------
#define BB    32
#define T1    129
#define TT    128
#define SS    256
#define EE    512
#define HH    1024
#define KK    128
#define VV    128
#define VOC   8000
#define VOCP  8064
#define K1    1664          // E + V + H
#define K2    2048          // H + H
#define KLOG  1152          // H + V
#define KQ1   416           // K1/4 per wave
#define NF1   13            // KQ1/32 k-fragments
#define KQ2   512
#define NF2   16
#define NBLK  256
#define NATT  32            // blocks doing attention

typedef __bf16 bf16x8 __attribute__((ext_vector_type(8)));
typedef float  f32x4  __attribute__((ext_vector_type(4)));

#define MFMA(a,b,c) __builtin_amdgcn_mfma_f32_16x16x32_bf16((a),(b),(c),0,0,0)

union bf8u { __hip_bfloat16 h[8]; bf16x8 v; };

__device__ __forceinline__ bf16x8 cvt8(float4 a, float4 b) {
    bf8u u;
    u.h[0] = __float2bfloat16(a.x); u.h[1] = __float2bfloat16(a.y);
    u.h[2] = __float2bfloat16(a.z); u.h[3] = __float2bfloat16(a.w);
    u.h[4] = __float2bfloat16(b.x); u.h[5] = __float2bfloat16(b.y);
    u.h[6] = __float2bfloat16(b.z); u.h[7] = __float2bfloat16(b.w);
    return u.v;
}

// ---------------- grid barrier (two-level, device scope) ----------------
// bar layout (ints): [g*32] 8 group counters (128B apart), [320] root, [384] generation
__device__ __forceinline__ void grid_barrier(int* bar, int bid, int& gen)
{
    __syncthreads();
    if (threadIdx.x == 0) {
        int my = gen;
        __threadfence();   // release all prior global writes (agent scope)
        int prev = __hip_atomic_fetch_add(&bar[(bid >> 5) * 32], 1,
                                          __ATOMIC_ACQ_REL, __HIP_MEMORY_SCOPE_AGENT);
        bool released = false;
        if (prev == 31) {
            int pr = __hip_atomic_fetch_add(&bar[320], 1,
                                            __ATOMIC_ACQ_REL, __HIP_MEMORY_SCOPE_AGENT);
            if (pr == 7) {
                #pragma unroll
                for (int i = 0; i < 8; ++i)
                    __hip_atomic_store(&bar[i * 32], 0, __ATOMIC_RELAXED, __HIP_MEMORY_SCOPE_AGENT);
                __hip_atomic_store(&bar[320], 0, __ATOMIC_RELAXED, __HIP_MEMORY_SCOPE_AGENT);
                __hip_atomic_fetch_add(&bar[384], 1, __ATOMIC_RELEASE, __HIP_MEMORY_SCOPE_AGENT);
                released = true;
            }
        }
        if (!released) {
            while (__hip_atomic_load(&bar[384], __ATOMIC_ACQUIRE, __HIP_MEMORY_SCOPE_AGENT) <= my)
                __builtin_amdgcn_s_sleep(2);
        }
        __threadfence();   // acquire: invalidate L1/L2 before data reads
        gen = my + 1;
    }
    __syncthreads();
}

// ---------------- prologue kernels ----------------
__global__ void pack_wout(const float* __restrict__ W, __hip_bfloat16* __restrict__ Wp)
{
    int v = blockIdx.y;
    int k = blockIdx.x * 256 + threadIdx.x;
    if (k >= KLOG) return;
    float w = (v < VOC) ? W[(size_t)v * KLOG + k] : 0.f;
    Wp[(size_t)v * KLOG + k] = __float2bfloat16(w);
}

__global__ void init_state(const float* __restrict__ enc,
                           __hip_bfloat16* __restrict__ A1,
                           __hip_bfloat16* __restrict__ A2,
                           int* __restrict__ bar)
{
    int i = blockIdx.x * 256 + threadIdx.x;
    if (i < 1024) bar[i] = 0;
    if (i >= BB * HH) return;
    int b = i >> 10, j = i & 1023;
    float e = enc[i];
    __hip_bfloat16 eb = __float2bfloat16(e);
    A2[(size_t)b * K2 + HH + j]        = eb;   // h2(-1)
    A1[(size_t)b * K1 + (EE + VV) + j] = eb;   // h1(-1) in step-0 A1
    if (j < VV) A1[(size_t)b * K1 + EE + j] = __float2bfloat16(0.f);  // ctx(-1)=0
}

__global__ void gather_emb(const int* __restrict__ tok, const float* __restrict__ emb,
                           __hip_bfloat16* __restrict__ A1)
{
    int bid = blockIdx.x;          // t*32 + b
    int t = bid >> 5, b = bid & 31;
    int id = tok[b * T1 + t];
    const float* er = emb + (size_t)id * EE;
    __hip_bfloat16* dst = A1 + (size_t)t * BB * K1 + (size_t)b * K1;
    for (int k = threadIdx.x; k < EE; k += 256)
        dst[k] = __float2bfloat16(er[k]);
}

// ---------------- persistent decoder ----------------
__global__ __launch_bounds__(256) void decoder_persistent(
    const float* __restrict__ Wih1, const float* __restrict__ Whh1, const float* __restrict__ b1v,
    const float* __restrict__ Wih2, const float* __restrict__ Whh2, const float* __restrict__ b2v,
    const float* __restrict__ Wq,   const float* __restrict__ bq,
    const float* __restrict__ keys, const float* __restrict__ vals,
    __hip_bfloat16* A1, __hip_bfloat16* A2,
    __hip_bfloat16* Alog, float* h2f, int* bar)
{
    const int bid = blockIdx.x;
    const int tid = threadIdx.x;
    const int wv  = tid >> 6;
    const int l   = tid & 63;
    const int l15 = l & 15, l4 = l >> 4;
    const int n0  = bid * 16;                 // packed col base (16 cols = 4 units x 4 gates)

    __shared__ float G[4][32][17];
    __shared__ float hs[HH];
    __shared__ float qs[KK];
    __shared__ float es[SS];
    __shared__ float red[256];

    // ---- load weight B-fragments into registers (fp32 -> bf16 once) ----
    bf16x8 w1f[NF1], w2f[NF2];
    {
        const int col  = n0 + l15;                       // packed row rp = 4*j + gate
        const int orow = (col & 3) * HH + (col >> 2);    // original row = gate*H + j
        #pragma unroll
        for (int i = 0; i < NF1; ++i) {
            int k0 = wv * KQ1 + i * 32 + l4 * 8;
            const float* s = (k0 < EE + VV) ? (Wih1 + (size_t)orow * (EE + VV) + k0)
                                            : (Whh1 + (size_t)orow * HH + (k0 - (EE + VV)));
            w1f[i] = cvt8(*(const float4*)s, *(const float4*)(s + 4));
        }
        #pragma unroll
        for (int i = 0; i < NF2; ++i) {
            int k0 = wv * KQ2 + i * 32 + l4 * 8;
            const float* s = (k0 < HH) ? (Wih2 + (size_t)orow * HH + k0)
                                       : (Whh2 + (size_t)orow * HH + (k0 - HH));
            w2f[i] = cvt8(*(const float4*)s, *(const float4*)(s + 4));
        }
    }

    // ---- per-thread cell state + bias (threads 0..127: b = tid&31, jl = tid>>5) ----
    float c1r = 0.f, c2r = 0.f;
    float gb1[4], gb2[4];
    {
        int jl = (tid >> 5) & 3;
        int j  = (n0 >> 2) + jl;
        #pragma unroll
        for (int g = 0; g < 4; ++g) { gb1[g] = b1v[g * HH + j]; gb2[g] = b2v[g * HH + j]; }
    }

    int gen = 0;
    f32x4 acc1a = {0.f,0.f,0.f,0.f}, acc1b = {0.f,0.f,0.f,0.f};
    const size_t a1s = (size_t)BB * K1;
    const size_t a2s = (size_t)BB * K2;

    // partial gates1 over emb + h1 sections (skip ctx frags)
    auto partial1 = [&](const __hip_bfloat16* Ab) {
        acc1a = (f32x4){0.f,0.f,0.f,0.f}; acc1b = (f32x4){0.f,0.f,0.f,0.f};
        #pragma unroll
        for (int i = 0; i < NF1; ++i) {
            int k0 = wv * KQ1 + i * 32;
            if (k0 >= EE && k0 < EE + VV) continue;          // ctx handled in phase 1
            const __hip_bfloat16* ap = Ab + (size_t)l15 * K1 + k0 + l4 * 8;
            bf16x8 a0 = *(const bf16x8*)ap;
            bf16x8 a1 = *(const bf16x8*)(ap + (size_t)16 * K1);
            acc1a = MFMA(a0, w1f[i], acc1a);
            acc1b = MFMA(a1, w1f[i], acc1b);
        }
    };

    if (bid >= NATT) partial1(A1);            // pre-loop partial for t=0

    #pragma unroll 1
    for (int t = 0; t < TT; ++t) {
        const __hip_bfloat16* A1t = A1 + (size_t)t * a1s;
        __hip_bfloat16* A1n   = A1 + (size_t)(t + 1) * a1s;
        __hip_bfloat16* A2c   = A2 + (size_t)(t & 1) * a2s;
        __hip_bfloat16* A2n   = A2 + (size_t)((t + 1) & 1) * a2s;
        __hip_bfloat16* AlogT = Alog + (size_t)t * BB * KLOG;

        // ======== phase 1: finish gates1 + cell1 + write h1 ========
        if (bid < NATT) {
            // attention blocks skipped phase-3 partial: full gates1 here
            acc1a = (f32x4){0.f,0.f,0.f,0.f}; acc1b = (f32x4){0.f,0.f,0.f,0.f};
            #pragma unroll
            for (int i = 0; i < NF1; ++i) {
                int k0 = wv * KQ1 + i * 32;
                const __hip_bfloat16* ap = A1t + (size_t)l15 * K1 + k0 + l4 * 8;
                bf16x8 a0 = *(const bf16x8*)ap;
                bf16x8 a1 = *(const bf16x8*)(ap + (size_t)16 * K1);
                acc1a = MFMA(a0, w1f[i], acc1a);
                acc1b = MFMA(a1, w1f[i], acc1b);
            }
        } else {
            // add ctx-section contribution (only wave 1 owns k in [512,640))
            #pragma unroll
            for (int i = 0; i < NF1; ++i) {
                int k0 = wv * KQ1 + i * 32;
                if (k0 >= EE && k0 < EE + VV) {
                    const __hip_bfloat16* ap = A1t + (size_t)l15 * K1 + k0 + l4 * 8;
                    bf16x8 a0 = *(const bf16x8*)ap;
                    bf16x8 a1 = *(const bf16x8*)(ap + (size_t)16 * K1);
                    acc1a = MFMA(a0, w1f[i], acc1a);
                    acc1b = MFMA(a1, w1f[i], acc1b);
                }
            }
        }
        #pragma unroll
        for (int r = 0; r < 4; ++r) {
            G[wv][l4 * 4 + r][l15]      = acc1a[r];
            G[wv][16 + l4 * 4 + r][l15] = acc1b[r];
        }
        __syncthreads();
        if (tid < 128) {
            int b = tid & 31, jl = tid >> 5;
            float g0 = G[0][b][4*jl+0] + G[1][b][4*jl+0] + G[2][b][4*jl+0] + G[3][b][4*jl+0] + gb1[0];
            float g1 = G[0][b][4*jl+1] + G[1][b][4*jl+1] + G[2][b][4*jl+1] + G[3][b][4*jl+1] + gb1[1];
            float g2 = G[0][b][4*jl+2] + G[1][b][4*jl+2] + G[2][b][4*jl+2] + G[3][b][4*jl+2] + gb1[2];
            float g3 = G[0][b][4*jl+3] + G[1][b][4*jl+3] + G[2][b][4*jl+3] + G[3][b][4*jl+3] + gb1[3];
            float si = 1.f / (1.f + __expf(-g0));
            float sf = 1.f / (1.f + __expf(-g1));
            float so = 1.f / (1.f + __expf(-g3));
            c1r = sf * c1r + si * tanhf(g2);
            float h = so * tanhf(c1r);
            int j = (n0 >> 2) + jl;
            __hip_bfloat16 hb = __float2bfloat16(h);
            A2c[(size_t)b * K2 + j] = hb;                               // LSTM2 input h1(t)
            if (t + 1 < TT) A1n[(size_t)b * K1 + EE + VV + j] = hb;     // next step h1 section
        }
        grid_barrier(bar, bid, gen);

        // ======== phase 2: LSTM2 + cell2 + write h2 ========
        {
            f32x4 acc2a = {0.f,0.f,0.f,0.f}, acc2b = {0.f,0.f,0.f,0.f};
            #pragma unroll
            for (int i = 0; i < NF2; ++i) {
                int k0 = wv * KQ2 + i * 32;
                const __hip_bfloat16* ap = A2c + (size_t)l15 * K2 + k0 + l4 * 8;
                bf16x8 a0 = *(const bf16x8*)ap;
                bf16x8 a1 = *(const bf16x8*)(ap + (size_t)16 * K2);
                acc2a = MFMA(a0, w2f[i], acc2a);
                acc2b = MFMA(a1, w2f[i], acc2b);
            }
            #pragma unroll
            for (int r = 0; r < 4; ++r) {
                G[wv][l4 * 4 + r][l15]      = acc2a[r];
                G[wv][16 + l4 * 4 + r][l15] = acc2b[r];
            }
            __syncthreads();
            if (tid < 128) {
                int b = tid & 31, jl = tid >> 5;
                float g0 = G[0][b][4*jl+0] + G[1][b][4*jl+0] + G[2][b][4*jl+0] + G[3][b][4*jl+0] + gb2[0];
                float g1 = G[0][b][4*jl+1] + G[1][b][4*jl+1] + G[2][b][4*jl+1] + G[3][b][4*jl+1] + gb2[1];
                float g2 = G[0][b][4*jl+2] + G[1][b][4*jl+2] + G[2][b][4*jl+2] + G[3][b][4*jl+2] + gb2[2];
                float g3 = G[0][b][4*jl+3] + G[1][b][4*jl+3] + G[2][b][4*jl+3] + G[3][b][4*jl+3] + gb2[3];
                float si = 1.f / (1.f + __expf(-g0));
                float sf = 1.f / (1.f + __expf(-g1));
                float so = 1.f / (1.f + __expf(-g3));
                c2r = sf * c2r + si * tanhf(g2);
                float h = so * tanhf(c2r);
                int j = (n0 >> 2) + jl;
                __hip_bfloat16 hb = __float2bfloat16(h);
                A2n[(size_t)b * K2 + HH + j] = hb;        // h2 for next step's LSTM2 input
                AlogT[(size_t)b * KLOG + j]  = hb;        // logits A-store
                h2f[b * HH + j] = h;                      // fp32 for attention
            }
            grid_barrier(bar, bid, gen);
        }

        // ======== phase 3: attention (blocks 0..31) || partial gates1(t+1) ========
        if (bid < NATT) {
            const int b = bid;
            for (int i = tid; i < HH; i += 256) hs[i] = h2f[b * HH + i];
            __syncthreads();
            {   // q = Wq @ h2 + bq (2 threads per k)
                int k = tid & 127, hf = tid >> 7;
                const float* wr = Wq + (size_t)k * HH + hf * 512;
                const float* hh = hs + hf * 512;
                float acc = 0.f;
                for (int j2 = 0; j2 < 512; j2 += 4)
                    acc += wr[j2]*hh[j2] + wr[j2+1]*hh[j2+1] + wr[j2+2]*hh[j2+2] + wr[j2+3]*hh[j2+3];
                red[tid] = acc;
            }
            __syncthreads();
            if (tid < KK) qs[tid] = red[tid] + red[tid + 128] + bq[tid];
            __syncthreads();
            {   // energy
                int s = tid;
                const float4* kr = (const float4*)(keys + ((size_t)b * SS + s) * KK);
                float acc = 0.f;
                for (int k4 = 0; k4 < KK / 4; ++k4) {
                    float4 kv = kr[k4];
                    acc += kv.x*qs[k4*4] + kv.y*qs[k4*4+1] + kv.z*qs[k4*4+2] + kv.w*qs[k4*4+3];
                }
                es[s] = acc;
            }
            __syncthreads();
            red[tid] = es[tid];
            __syncthreads();
            for (int off = 128; off > 0; off >>= 1) {
                if (tid < off) red[tid] = fmaxf(red[tid], red[tid + off]);
                __syncthreads();
            }
            float mx = red[0];
            __syncthreads();
            float ev = __expf(es[tid] - mx);
            es[tid] = ev; red[tid] = ev;
            __syncthreads();
            for (int off = 128; off > 0; off >>= 1) {
                if (tid < off) red[tid] += red[tid + off];
                __syncthreads();
            }
            float inv = 1.f / red[0];
            __syncthreads();
            {   // context
                int v = tid & 127, hf = tid >> 7;
                const float* vb = vals + ((size_t)b * SS + hf * 128) * VV;
                float acc = 0.f;
                for (int s = 0; s < 128; ++s) acc += es[hf * 128 + s] * vb[(size_t)s * VV + v];
                red[tid] = acc;
            }
            __syncthreads();
            if (tid < VV) {
                float cv = (red[tid] + red[tid + 128]) * inv;
                __hip_bfloat16 cb = __float2bfloat16(cv);
                if (t + 1 < TT) A1n[(size_t)b * K1 + EE + tid] = cb;
                AlogT[(size_t)b * KLOG + HH + tid] = cb;
            }
        } else if (t + 1 < TT) {
            partial1(A1n);           // emb(t+1) + h1(t) sections
        }
        grid_barrier(bar, bid, gen);
    }
}

// ---------------- deferred logits GEMM ----------------
__global__ __launch_bounds__(256) void logits_gemm(
    const __hip_bfloat16* __restrict__ Alog,
    const __hip_bfloat16* __restrict__ W,
    const float* __restrict__ bout,
    float* __restrict__ out)
{
    int n0 = blockIdx.x * 128;
    int m0 = blockIdx.y * 128;
    int wv = threadIdx.x >> 6, l = threadIdx.x & 63;
    int l15 = l & 15, l4 = l >> 4;

    f32x4 acc[8][2] = {};
    const __hip_bfloat16* Ap = Alog + (size_t)(m0 + l15) * KLOG + l4 * 8;
    const __hip_bfloat16* Bp = W    + (size_t)(n0 + wv * 32 + l15) * KLOG + l4 * 8;

    for (int kt = 0; kt < KLOG; kt += 32) {
        bf16x8 b0 = *(const bf16x8*)(Bp + kt);
        bf16x8 b1 = *(const bf16x8*)(Bp + (size_t)16 * KLOG + kt);
        #pragma unroll
        for (int ms = 0; ms < 8; ++ms) {
            bf16x8 a = *(const bf16x8*)(Ap + (size_t)ms * 16 * KLOG + kt);
            acc[ms][0] = MFMA(a, b0, acc[ms][0]);
            acc[ms][1] = MFMA(a, b1, acc[ms][1]);
        }
    }

    #pragma unroll
    for (int ms = 0; ms < 8; ++ms) {
        #pragma unroll
        for (int ns = 0; ns < 2; ++ns) {
            int col = n0 + wv * 32 + ns * 16 + l15;
            if (col < VOC) {
                float bias = bout[col];
                #pragma unroll
                for (int r = 0; r < 4; ++r) {
                    int m = m0 + ms * 16 + l4 * 4 + r;
                    int b = m & 31, t = m >> 5;
                    out[((size_t)b * TT + t) * VOC + col] = acc[ms][ns][r] + bias;
                }
            }
        }
    }
}

// ---------------- host ----------------
extern "C" void kernel_launch(void* const* d_in, const int* in_sizes, int n_in,
                              void* d_out, int out_size, void* d_ws, size_t ws_size,
                              hipStream_t stream)
{
    (void)in_sizes; (void)n_in; (void)out_size; (void)ws_size;
    const int*   dec  = (const int*)  d_in[0];
    const float* enc  = (const float*)d_in[2];
    const float* keys = (const float*)d_in[3];
    const float* vals = (const float*)d_in[4];
    const float* emb  = (const float*)d_in[5];
    const float* Wih1 = (const float*)d_in[6];
    const float* Whh1 = (const float*)d_in[7];
    const float* b1   = (const float*)d_in[8];
    const float* Wih2 = (const float*)d_in[9];
    const float* Whh2 = (const float*)d_in[10];
    const float* b2   = (const float*)d_in[11];
    const float* Wq   = (const float*)d_in[12];
    const float* bq   = (const float*)d_in[13];
    const float* Wout = (const float*)d_in[14];
    const float* bout = (const float*)d_in[15];
    float* out = (float*)d_out;

    char* p = (char*)d_ws;
    __hip_bfloat16* WoutP = (__hip_bfloat16*)p; p += (size_t)VOCP * KLOG * 2;      // 18.6 MB
    __hip_bfloat16* A1    = (__hip_bfloat16*)p; p += (size_t)TT * BB * K1 * 2;     // 13.6 MB
    __hip_bfloat16* A2    = (__hip_bfloat16*)p; p += (size_t)2 * BB * K2 * 2;      // 256 KB
    __hip_bfloat16* Alog  = (__hip_bfloat16*)p; p += (size_t)TT * BB * KLOG * 2;   // 9.4 MB
    float* h2f = (float*)p; p += (size_t)BB * HH * 4;
    int*   bar = (int*)p;   p += 4096;

    pack_wout  <<<dim3((KLOG + 255) / 256, VOCP), 256, 0, stream>>>(Wout, WoutP);
    init_state <<<dim3(128), 256, 0, stream>>>(enc, A1, A2, bar);
    gather_emb <<<dim3(TT * BB), 256, 0, stream>>>(dec, emb, A1);

    decoder_persistent<<<dim3(NBLK), 256, 0, stream>>>(
        Wih1, Whh1, b1, Wih2, Whh2, b2, Wq, bq, keys, vals,
        A1, A2, Alog, h2f, bar);

    logits_gemm<<<dim3(VOCP / 128, (BB * TT) / 128), 256, 0, stream>>>(Alog, WoutP, bout, out);
}

// Round 3
// 5060.748 us; speedup vs baseline: 3.9461x; 3.9461x over previous
//
#include <hip/hip_runtime.h>
#include <hip/hip_bf16.h>
#include <cstddef>

// ---------------- problem constants ----------------
#define BB    32
#define T1    129
#define TT    128
#define SS    256
#define EE    512
#define HH    1024
#define KK    128
#define VV    128
#define VOC   8000
#define VOCP  8064
#define K1    1664          // E + V + H
#define K2    2048          // H + H
#define KLOG  1152          // H + V
#define NF1   13            // frags per wave, GEMM1 (52/4)
#define NF2   16            // frags per wave, GEMM2 (64/4)
#define NBLK  256
#define NATT  32

typedef __bf16 bf16x8 __attribute__((ext_vector_type(8)));
typedef float  f32x4  __attribute__((ext_vector_type(4)));

#define MFMA(a,b,c) __builtin_amdgcn_mfma_f32_16x16x32_bf16((a),(b),(c),0,0,0)

// Coherent (cross-XCD) access primitives: write-through / read-through the
// memory-side Infinity Cache, bypassing the non-coherent per-XCD L2s.
#define CLOAD(dst, p) asm volatile("global_load_dwordx4 %0, %1, off sc0 sc1" : "=v"(dst) : "v"(p))

__device__ __forceinline__ int coh_load_i32(const int* p) {
    int r;
    asm volatile("global_load_dword %0, %1, off sc0 sc1\n\ts_waitcnt vmcnt(0)"
                 : "=v"(r) : "v"(p) : "memory");
    return r;
}
__device__ __forceinline__ void cstore_u16(__hip_bfloat16* p, __hip_bfloat16 v) {
    union { __hip_bfloat16 h; unsigned short u; } cv; cv.h = v;
    unsigned int val = cv.u;
    asm volatile("global_store_short %0, %1, off sc0 sc1" :: "v"(p), "v"(val) : "memory");
}
__device__ __forceinline__ void cstore_f32(float* p, float v) {
    asm volatile("global_store_dword %0, %1, off sc0 sc1" :: "v"(p), "v"(v) : "memory");
}

union bf8u { __hip_bfloat16 h[8]; bf16x8 v; };

__device__ __forceinline__ bf16x8 cvt8(float4 a, float4 b) {
    bf8u u;
    u.h[0] = __float2bfloat16(a.x); u.h[1] = __float2bfloat16(a.y);
    u.h[2] = __float2bfloat16(a.z); u.h[3] = __float2bfloat16(a.w);
    u.h[4] = __float2bfloat16(b.x); u.h[5] = __float2bfloat16(b.y);
    u.h[6] = __float2bfloat16(b.z); u.h[7] = __float2bfloat16(b.w);
    return u.v;
}

// Coherent-load + MFMA over slots [SBASE, SBASE+NS). Slot s covers
// k0 = (wv + 4*(SBASE+s))*32 (round-robin k-map, uniform across waves).
template<int SBASE, int NS>
__device__ __forceinline__ void coh_mfma(const __hip_bfloat16* rA, const __hip_bfloat16* rB,
                                         int wv, const bf16x8* wf, f32x4& a0, f32x4& a1)
{
    bf16x8 fA[NS], fB[NS];
    #pragma unroll
    for (int s = 0; s < NS; ++s) {
        int k0 = (wv + 4 * (SBASE + s)) * 32;
        CLOAD(fA[s], rA + k0);
        CLOAD(fB[s], rB + k0);
    }
    asm volatile("s_waitcnt vmcnt(0)" ::: "memory");
    __builtin_amdgcn_sched_barrier(0);
    #pragma unroll
    for (int s = 0; s < NS; ++s) {
        a0 = MFMA(fA[s], wf[SBASE + s], a0);
        a1 = MFMA(fB[s], wf[SBASE + s], a1);
    }
}

// ---------------- fence-free grid barrier ----------------
// All fresh data was stored write-through (sc0 sc1); after vmcnt(0) it is at
// the coherence point. Counters: relaxed agent RMWs (execute at MALL).
// bar layout: [g*32] 8 group counters, [320] root, [384] generation. Monotonic.
__device__ __forceinline__ void grid_barrier(int* bar, int bid, int& gen)
{
    asm volatile("s_waitcnt vmcnt(0)" ::: "memory");   // per-wave: drain my stores
    __syncthreads();
    if (threadIdx.x == 0) {
        int target = gen + 1;
        int prev = __hip_atomic_fetch_add(&bar[(bid >> 5) * 32], 1,
                                          __ATOMIC_RELAXED, __HIP_MEMORY_SCOPE_AGENT);
        if (((prev + 1) & 31) == 0) {
            int pr = __hip_atomic_fetch_add(&bar[320], 1,
                                            __ATOMIC_RELAXED, __HIP_MEMORY_SCOPE_AGENT);
            if (((pr + 1) & 7) == 0)
                __hip_atomic_fetch_add(&bar[384], 1,
                                       __ATOMIC_RELAXED, __HIP_MEMORY_SCOPE_AGENT);
        }
        while (coh_load_i32(&bar[384]) < target)
            __builtin_amdgcn_s_sleep(4);
        gen = target;
    }
    __syncthreads();
}

// ---------------- prologue kernels ----------------
__global__ void pack_wout(const float* __restrict__ W, __hip_bfloat16* __restrict__ Wp)
{
    int v = blockIdx.y;
    int k = blockIdx.x * 256 + threadIdx.x;
    if (k >= KLOG) return;
    float w = (v < VOC) ? W[(size_t)v * KLOG + k] : 0.f;
    Wp[(size_t)v * KLOG + k] = __float2bfloat16(w);
}

__global__ void init_state(const float* __restrict__ enc,
                           __hip_bfloat16* __restrict__ A1,
                           __hip_bfloat16* __restrict__ A2,
                           int* __restrict__ bar)
{
    int i = blockIdx.x * 256 + threadIdx.x;
    if (i < 1024) bar[i] = 0;                  // reset barrier every launch
    if (i >= BB * HH) return;
    int b = i >> 10, j = i & 1023;
    float e = enc[i];
    __hip_bfloat16 eb = __float2bfloat16(e);
    A2[(size_t)b * K2 + HH + j]        = eb;   // h2(-1), parity-0 buffer
    A1[(size_t)b * K1 + (EE + VV) + j] = eb;   // h1(-1), step-0 A1
    if (j < VV) A1[(size_t)b * K1 + EE + j] = __float2bfloat16(0.f);  // ctx(-1)=0
}

__global__ void gather_emb(const int* __restrict__ tok, const float* __restrict__ emb,
                           __hip_bfloat16* __restrict__ A1)
{
    int bid = blockIdx.x;          // t*32 + b
    int t = bid >> 5, b = bid & 31;
    int id = tok[b * T1 + t];
    const float* er = emb + (size_t)id * EE;
    __hip_bfloat16* dst = A1 + (size_t)t * BB * K1 + (size_t)b * K1;
    for (int k = threadIdx.x; k < EE; k += 256)
        dst[k] = __float2bfloat16(er[k]);
}

// ---------------- persistent decoder ----------------
__global__ __launch_bounds__(256) void decoder_persistent(
    const float* __restrict__ Wih1, const float* __restrict__ Whh1, const float* __restrict__ b1v,
    const float* __restrict__ Wih2, const float* __restrict__ Whh2, const float* __restrict__ b2v,
    const float* __restrict__ Wq,   const float* __restrict__ bq,
    const float* __restrict__ keys, const float* __restrict__ vals,
    __hip_bfloat16* A1, __hip_bfloat16* A2,
    __hip_bfloat16* Alog, float* h2f, int* bar)
{
    const int bid = blockIdx.x;
    const int tid = threadIdx.x;
    const int wv  = tid >> 6;
    const int l   = tid & 63;
    const int l15 = l & 15, l4 = l >> 4;
    const int n0  = bid * 16;                 // packed col base (16 cols = 4 units x 4 gates)

    __shared__ float G[4][32][17];
    __shared__ float hs[HH];
    __shared__ float qs[KK];
    __shared__ float es[SS];
    __shared__ float red[256];

    // ---- weight B-fragments into registers (round-robin k-map) ----
    bf16x8 w1f[NF1], w2f[NF2];
    {
        const int col  = n0 + l15;                       // packed row rp = 4*j + gate
        const int orow = (col & 3) * HH + (col >> 2);    // original row = gate*H + j
        #pragma unroll
        for (int s = 0; s < NF1; ++s) {
            int k0 = (wv + 4 * s) * 32 + l4 * 8;
            const float* src = (k0 < EE + VV) ? (Wih1 + (size_t)orow * (EE + VV) + k0)
                                              : (Whh1 + (size_t)orow * HH + (k0 - (EE + VV)));
            w1f[s] = cvt8(*(const float4*)src, *(const float4*)(src + 4));
        }
        #pragma unroll
        for (int s = 0; s < NF2; ++s) {
            int k0 = (wv + 4 * s) * 32 + l4 * 8;
            const float* src = (k0 < HH) ? (Wih2 + (size_t)orow * HH + k0)
                                         : (Whh2 + (size_t)orow * HH + (k0 - HH));
            w2f[s] = cvt8(*(const float4*)src, *(const float4*)(src + 4));
        }
    }

    // ---- per-thread cell state + bias (threads 0..127: b = tid&31, jl = tid>>5) ----
    float c1r = 0.f, c2r = 0.f;
    float gb1[4], gb2[4];
    {
        int jl = (tid >> 5) & 3;
        int j  = (n0 >> 2) + jl;
        #pragma unroll
        for (int g = 0; g < 4; ++g) { gb1[g] = b1v[g * HH + j]; gb2[g] = b2v[g * HH + j]; }
    }

    int gen = 0;
    const size_t a1s = (size_t)BB * K1;
    const size_t a2s = (size_t)BB * K2;

    #pragma unroll 1
    for (int t = 0; t < TT; ++t) {
        const __hip_bfloat16* A1t = A1 + (size_t)t * a1s;
        __hip_bfloat16* A1n   = A1 + (size_t)(t + 1) * a1s;
        __hip_bfloat16* A2c   = A2 + (size_t)(t & 1) * a2s;
        __hip_bfloat16* A2n   = A2 + (size_t)((t + 1) & 1) * a2s;
        __hip_bfloat16* AlogT = Alog + (size_t)t * BB * KLOG;

        // ======== phase 1: gates1 + cell1 -> h1 ========
        {
            f32x4 acc0 = {0.f,0.f,0.f,0.f}, acc1 = {0.f,0.f,0.f,0.f};
            const __hip_bfloat16* rA = A1t + (size_t)l15 * K1 + l4 * 8;
            const __hip_bfloat16* rB = rA + (size_t)16 * K1;
            // slots 0..3: emb section (read-only, stale-safe normal loads)
            #pragma unroll
            for (int s = 0; s < 4; ++s) {
                int k0 = (wv + 4 * s) * 32;
                bf16x8 a0 = *(const bf16x8*)(rA + k0);
                bf16x8 a1 = *(const bf16x8*)(rB + k0);
                acc0 = MFMA(a0, w1f[s], acc0);
                acc1 = MFMA(a1, w1f[s], acc1);
            }
            // slots 4..12: ctx + h1 sections (fresh -> coherent loads)
            coh_mfma<4, 9>(rA, rB, wv, w1f, acc0, acc1);

            #pragma unroll
            for (int r = 0; r < 4; ++r) {
                G[wv][l4 * 4 + r][l15]      = acc0[r];
                G[wv][16 + l4 * 4 + r][l15] = acc1[r];
            }
        }
        __syncthreads();
        if (tid < 128) {
            int b = tid & 31, jl = tid >> 5;
            float g0 = G[0][b][4*jl+0] + G[1][b][4*jl+0] + G[2][b][4*jl+0] + G[3][b][4*jl+0] + gb1[0];
            float g1 = G[0][b][4*jl+1] + G[1][b][4*jl+1] + G[2][b][4*jl+1] + G[3][b][4*jl+1] + gb1[1];
            float g2 = G[0][b][4*jl+2] + G[1][b][4*jl+2] + G[2][b][4*jl+2] + G[3][b][4*jl+2] + gb1[2];
            float g3 = G[0][b][4*jl+3] + G[1][b][4*jl+3] + G[2][b][4*jl+3] + G[3][b][4*jl+3] + gb1[3];
            float si = 1.f / (1.f + __expf(-g0));
            float sf = 1.f / (1.f + __expf(-g1));
            float so = 1.f / (1.f + __expf(-g3));
            c1r = sf * c1r + si * tanhf(g2);
            float h = so * tanhf(c1r);
            int j = (n0 >> 2) + jl;
            __hip_bfloat16 hb = __float2bfloat16(h);
            cstore_u16(&A2c[(size_t)b * K2 + j], hb);                      // LSTM2 input h1(t)
            if (t + 1 < TT) cstore_u16(&A1n[(size_t)b * K1 + EE + VV + j], hb);
        }
        grid_barrier(bar, bid, gen);

        // ======== phase 2: gates2 + cell2 -> h2 ========
        {
            f32x4 acc0 = {0.f,0.f,0.f,0.f}, acc1 = {0.f,0.f,0.f,0.f};
            const __hip_bfloat16* rA = A2c + (size_t)l15 * K2 + l4 * 8;
            const __hip_bfloat16* rB = rA + (size_t)16 * K2;
            coh_mfma<0, 8>(rA, rB, wv, w2f, acc0, acc1);   // h1 half (fresh)
            coh_mfma<8, 8>(rA, rB, wv, w2f, acc0, acc1);   // h2(t-1) half (fresh)
            #pragma unroll
            for (int r = 0; r < 4; ++r) {
                G[wv][l4 * 4 + r][l15]      = acc0[r];
                G[wv][16 + l4 * 4 + r][l15] = acc1[r];
            }
        }
        __syncthreads();
        if (tid < 128) {
            int b = tid & 31, jl = tid >> 5;
            float g0 = G[0][b][4*jl+0] + G[1][b][4*jl+0] + G[2][b][4*jl+0] + G[3][b][4*jl+0] + gb2[0];
            float g1 = G[0][b][4*jl+1] + G[1][b][4*jl+1] + G[2][b][4*jl+1] + G[3][b][4*jl+1] + gb2[1];
            float g2 = G[0][b][4*jl+2] + G[1][b][4*jl+2] + G[2][b][4*jl+2] + G[3][b][4*jl+2] + gb2[2];
            float g3 = G[0][b][4*jl+3] + G[1][b][4*jl+3] + G[2][b][4*jl+3] + G[3][b][4*jl+3] + gb2[3];
            float si = 1.f / (1.f + __expf(-g0));
            float sf = 1.f / (1.f + __expf(-g1));
            float so = 1.f / (1.f + __expf(-g3));
            c2r = sf * c2r + si * tanhf(g2);
            float h = so * tanhf(c2r);
            int j = (n0 >> 2) + jl;
            __hip_bfloat16 hb = __float2bfloat16(h);
            cstore_u16(&A2n[(size_t)b * K2 + HH + j], hb);   // h2 -> next-step LSTM2 input
            AlogT[(size_t)b * KLOG + j] = hb;                // logits A-store (post-kernel)
            cstore_f32(&h2f[b * HH + j], h);                 // fp32 for attention
        }
        grid_barrier(bar, bid, gen);

        // ======== phase 3: attention (blocks 0..31) ========
        if (bid < NATT) {
            const int b = bid;
            {   // stage h2 (fresh -> coherent)
                float4 hv;
                const float* hp = h2f + (size_t)b * HH + tid * 4;
                CLOAD(hv, hp);
                asm volatile("s_waitcnt vmcnt(0)" ::: "memory");
                __builtin_amdgcn_sched_barrier(0);
                *(float4*)&hs[tid * 4] = hv;
            }
            __syncthreads();
            {   // q = Wq @ h2 + bq (2 threads per k)
                int k = tid & 127, hf = tid >> 7;
                const float* wr = Wq + (size_t)k * HH + hf * 512;
                const float* hh = hs + hf * 512;
                float acc = 0.f;
                for (int j2 = 0; j2 < 512; j2 += 4)
                    acc += wr[j2]*hh[j2] + wr[j2+1]*hh[j2+1] + wr[j2+2]*hh[j2+2] + wr[j2+3]*hh[j2+3];
                red[tid] = acc;
            }
            __syncthreads();
            if (tid < KK) qs[tid] = red[tid] + red[tid + 128] + bq[tid];
            __syncthreads();
            {   // energy
                int s = tid;
                const float4* kr = (const float4*)(keys + ((size_t)b * SS + s) * KK);
                float acc = 0.f;
                for (int k4 = 0; k4 < KK / 4; ++k4) {
                    float4 kv = kr[k4];
                    acc += kv.x*qs[k4*4] + kv.y*qs[k4*4+1] + kv.z*qs[k4*4+2] + kv.w*qs[k4*4+3];
                }
                es[s] = acc;
            }
            __syncthreads();
            red[tid] = es[tid];
            __syncthreads();
            for (int off = 128; off > 0; off >>= 1) {
                if (tid < off) red[tid] = fmaxf(red[tid], red[tid + off]);
                __syncthreads();
            }
            float mx = red[0];
            __syncthreads();
            float ev = __expf(es[tid] - mx);
            es[tid] = ev; red[tid] = ev;
            __syncthreads();
            for (int off = 128; off > 0; off >>= 1) {
                if (tid < off) red[tid] += red[tid + off];
                __syncthreads();
            }
            float inv = 1.f / red[0];
            __syncthreads();
            {   // context
                int v = tid & 127, hf = tid >> 7;
                const float* vb = vals + ((size_t)b * SS + hf * 128) * VV;
                float acc = 0.f;
                for (int s = 0; s < 128; ++s) acc += es[hf * 128 + s] * vb[(size_t)s * VV + v];
                red[tid] = acc;
            }
            __syncthreads();
            if (tid < VV) {
                float cv = (red[tid] + red[tid + 128]) * inv;
                __hip_bfloat16 cb = __float2bfloat16(cv);
                if (t + 1 < TT) cstore_u16(&A1n[(size_t)b * K1 + EE + tid], cb);
                AlogT[(size_t)b * KLOG + HH + tid] = cb;     // post-kernel consumer
            }
        }
        grid_barrier(bar, bid, gen);
    }
}

// ---------------- deferred logits GEMM ----------------
__global__ __launch_bounds__(256) void logits_gemm(
    const __hip_bfloat16* __restrict__ Alog,
    const __hip_bfloat16* __restrict__ W,
    const float* __restrict__ bout,
    float* __restrict__ out)
{
    int n0 = blockIdx.x * 128;
    int m0 = blockIdx.y * 128;
    int wv = threadIdx.x >> 6, l = threadIdx.x & 63;
    int l15 = l & 15, l4 = l >> 4;

    f32x4 acc[8][2] = {};
    const __hip_bfloat16* Ap = Alog + (size_t)(m0 + l15) * KLOG + l4 * 8;
    const __hip_bfloat16* Bp = W    + (size_t)(n0 + wv * 32 + l15) * KLOG + l4 * 8;

    for (int kt = 0; kt < KLOG; kt += 32) {
        bf16x8 b0 = *(const bf16x8*)(Bp + kt);
        bf16x8 b1 = *(const bf16x8*)(Bp + (size_t)16 * KLOG + kt);
        #pragma unroll
        for (int ms = 0; ms < 8; ++ms) {
            bf16x8 a = *(const bf16x8*)(Ap + (size_t)ms * 16 * KLOG + kt);
            acc[ms][0] = MFMA(a, b0, acc[ms][0]);
            acc[ms][1] = MFMA(a, b1, acc[ms][1]);
        }
    }

    #pragma unroll
    for (int ms = 0; ms < 8; ++ms) {
        #pragma unroll
        for (int ns = 0; ns < 2; ++ns) {
            int col = n0 + wv * 32 + ns * 16 + l15;
            if (col < VOC) {
                float bias = bout[col];
                #pragma unroll
                for (int r = 0; r < 4; ++r) {
                    int m = m0 + ms * 16 + l4 * 4 + r;
                    int b = m & 31, t = m >> 5;
                    out[((size_t)b * TT + t) * VOC + col] = acc[ms][ns][r] + bias;
                }
            }
        }
    }
}

// ---------------- host ----------------
extern "C" void kernel_launch(void* const* d_in, const int* in_sizes, int n_in,
                              void* d_out, int out_size, void* d_ws, size_t ws_size,
                              hipStream_t stream)
{
    (void)in_sizes; (void)n_in; (void)out_size; (void)ws_size;
    const int*   dec  = (const int*)  d_in[0];
    const float* enc  = (const float*)d_in[2];
    const float* keys = (const float*)d_in[3];
    const float* vals = (const float*)d_in[4];
    const float* emb  = (const float*)d_in[5];
    const float* Wih1 = (const float*)d_in[6];
    const float* Whh1 = (const float*)d_in[7];
    const float* b1   = (const float*)d_in[8];
    const float* Wih2 = (const float*)d_in[9];
    const float* Whh2 = (const float*)d_in[10];
    const float* b2   = (const float*)d_in[11];
    const float* Wq   = (const float*)d_in[12];
    const float* bq   = (const float*)d_in[13];
    const float* Wout = (const float*)d_in[14];
    const float* bout = (const float*)d_in[15];
    float* out = (float*)d_out;

    char* p = (char*)d_ws;
    __hip_bfloat16* WoutP = (__hip_bfloat16*)p; p += (size_t)VOCP * KLOG * 2;      // 18.6 MB
    __hip_bfloat16* A1    = (__hip_bfloat16*)p; p += (size_t)TT * BB * K1 * 2;     // 13.6 MB
    __hip_bfloat16* A2    = (__hip_bfloat16*)p; p += (size_t)2 * BB * K2 * 2;      // 256 KB
    __hip_bfloat16* Alog  = (__hip_bfloat16*)p; p += (size_t)TT * BB * KLOG * 2;   // 9.4 MB
    float* h2f = (float*)p; p += (size_t)BB * HH * 4;
    int*   bar = (int*)p;   p += 4096;

    pack_wout  <<<dim3((KLOG + 255) / 256, VOCP), 256, 0, stream>>>(Wout, WoutP);
    init_state <<<dim3(128), 256, 0, stream>>>(enc, A1, A2, bar);
    gather_emb <<<dim3(TT * BB), 256, 0, stream>>>(dec, emb, A1);

    decoder_persistent<<<dim3(NBLK), 256, 0, stream>>>(
        Wih1, Whh1, b1, Wih2, Whh2, b2, Wq, bq, keys, vals,
        A1, A2, Alog, h2f, bar);

    logits_gemm<<<dim3(VOCP / 128, (BB * TT) / 128), 256, 0, stream>>>(Alog, WoutP, bout, out);
}